// Round 3
// baseline (80.102 us; speedup 1.0000x reference)
//
#include <hip/hip_runtime.h>
#include <hip/hip_cooperative_groups.h>
#include <math.h>

namespace cg = cooperative_groups;

#define N   512
#define DI  128
#define DO  128

// ---------------------------------------------------------------------------
// Single cooperative kernel, 256 blocks x 512 threads (1 block/CU).
//   phase 0: WT[k][c] = (c<128 ? Wf[c][k] : Wf[c-128][128+k])   (blocks 0..63)
//   phase 1: fsrc/ftgt = x @ WT  (+ s,t attention scalars)      (2 rows/block)
//   phase 2: softmax over masked scores + weighted ReLU contraction
// d_ws layout (floats): WT[128*256] | fsrc[512*128] | ftgt[512*128] | s[512] | t[512]
// ---------------------------------------------------------------------------
__global__ __launch_bounds__(512) void gat_fused_kernel(
    const float* __restrict__ x,
    const int*   __restrict__ adj,
    const float* __restrict__ Wf,
    const float* __restrict__ bf,
    const float* __restrict__ Ww,
    const float* __restrict__ bw,
    float* __restrict__ out,      // [0..N*DO) = o, [N*DO..) = a_att
    float* __restrict__ WT,
    float* __restrict__ fsrc,
    float* __restrict__ ftgt,
    float* __restrict__ s,
    float* __restrict__ t)
{
    cg::grid_group grid = cg::this_grid();
    const int b   = blockIdx.x;
    const int tid = threadIdx.x;   // 0..511

    __shared__ float accbuf[2][4][256];    // 8 KB  (proj k-slice partials)
    __shared__ float p[N][2];              // 4 KB
    __shared__ float red[16][2][DO];       // 16 KB
    __shared__ float rmax[2][4], rsum[2][4];

    // ---------------- phase 0: transpose Wf -> WT ----------------
    if (b < 64) {
        const int e = b * 512 + tid;       // 0..32767
        const int k = e >> 8, c = e & 255;
        WT[e] = Wf[(c & 127) * 256 + (c >> 7) * 128 + k];
    }
    grid.sync();

    // ---------------- phase 1: projections ----------------
    const int j0 = b * 2;   // this block's two rows (used as i0 in phase 2)
    {
        const int r   = tid >> 8;          // row 0/1
        const int ks  = (tid >> 6) & 3;    // k-slice 0..3 (32 k's each)
        const int cg4 = (tid & 63) * 4;    // column base (float4)
        const float* __restrict__ xr = x + (j0 + r) * DI + ks * 32;

        float ax = 0.f, ay = 0.f, az = 0.f, aw = 0.f;
#pragma unroll
        for (int kk = 0; kk < 32; ++kk) {
            const float4 w4 = *(const float4*)&WT[(ks * 32 + kk) * 256 + cg4];
            const float  xv = xr[kk];      // wave-uniform -> scalar load
            ax += xv * w4.x; ay += xv * w4.y; az += xv * w4.z; aw += xv * w4.w;
        }
        *(float4*)&accbuf[r][ks][cg4] = make_float4(ax, ay, az, aw);

        // attention scalars: waves 0..3 -> (row, s|t)
        const int w = tid >> 6;
        if (w < 4) {
            const int row  = j0 + (w >> 1);
            const int half = (w & 1) * DI;
            const int l    = tid & 63;
            float v = x[row * DI + l] * Ww[half + l]
                    + x[row * DI + 64 + l] * Ww[half + 64 + l];
            for (int off = 32; off >= 1; off >>= 1)
                v += __shfl_down(v, off);
            if (l == 0) {
                if ((w & 1) == 0) s[row] = v;
                else              t[row] = v;
            }
        }
        __syncthreads();

        if (tid < 128) {
            const int r2 = tid >> 6;
            const int cg = tid & 63;
            const float4 a0 = *(const float4*)&accbuf[r2][0][cg * 4];
            const float4 a1 = *(const float4*)&accbuf[r2][1][cg * 4];
            const float4 a2 = *(const float4*)&accbuf[r2][2][cg * 4];
            const float4 a3 = *(const float4*)&accbuf[r2][3][cg * 4];
            const float4 sm = make_float4(a0.x + a1.x + a2.x + a3.x,
                                          a0.y + a1.y + a2.y + a3.y,
                                          a0.z + a1.z + a2.z + a3.z,
                                          a0.w + a1.w + a2.w + a3.w);
            if (cg < 32) *(float4*)&fsrc[(j0 + r2) * DO + cg * 4] = sm;
            else         *(float4*)&ftgt[(j0 + r2) * DO + (cg - 32) * 4] = sm;
        }
    }
    grid.sync();

    // ---------------- phase 2: softmax + weighted ReLU contraction ----------------
    const int i0 = j0;
    {
        const int r  = tid >> 8;       // row 0/1
        const int jj = tid & 255;      // handles j = jj, jj+256
        const int i  = i0 + r;
        const float t_i = t[i] + bw[0];

        const float sc0 = s[jj] + t_i;
        const float sc1 = s[jj + 256] + t_i;
        const float v0 = (adj[i * N + jj] > 0)       ? sc0 : -1e16f;
        const float v1 = (adj[i * N + jj + 256] > 0) ? sc1 : -1e16f;

        const int wr = (tid >> 6) & 3;
        float m = fmaxf(v0, v1);
        for (int off = 32; off >= 1; off >>= 1)
            m = fmaxf(m, __shfl_down(m, off));
        if ((tid & 63) == 0) rmax[r][wr] = m;
        __syncthreads();
        m = fmaxf(fmaxf(rmax[r][0], rmax[r][1]), fmaxf(rmax[r][2], rmax[r][3]));

        const float e0 = __expf(v0 - m);
        const float e1 = __expf(v1 - m);
        float sum = e0 + e1;
        for (int off = 32; off >= 1; off >>= 1)
            sum += __shfl_down(sum, off);
        if ((tid & 63) == 0) rsum[r][wr] = sum;
        __syncthreads();
        sum = rsum[r][0] + rsum[r][1] + rsum[r][2] + rsum[r][3];
        const float inv = 1.0f / sum;

        const float p0 = e0 * inv;
        const float p1 = e1 * inv;
        p[jj][r]       = p0;
        p[jj + 256][r] = p1;
        out[N * DO + i * N + jj]       = p0;
        out[N * DO + i * N + jj + 256] = p1;
        __syncthreads();

        // weighted ReLU contraction: 16 j-groups x 32 d-float4-groups
        const int c4 = (tid & 31) * 4;
        const int jg = tid >> 5;

        const float4 fA = *(const float4*)&ftgt[i0 * DO + c4];
        const float4 fB = *(const float4*)&ftgt[(i0 + 1) * DO + c4];
        const float4 bb = *(const float4*)&bf[c4];
        const float ftbAx = fA.x + bb.x, ftbAy = fA.y + bb.y,
                    ftbAz = fA.z + bb.z, ftbAw = fA.w + bb.w;
        const float ftbBx = fB.x + bb.x, ftbBy = fB.y + bb.y,
                    ftbBz = fB.z + bb.z, ftbBw = fB.w + bb.w;

        float ax = 0.f, ay = 0.f, az = 0.f, aw = 0.f;
        float bx = 0.f, by = 0.f, bz = 0.f, bw_ = 0.f;

        const int jstart = jg * 32;
#pragma unroll 8
        for (int j = jstart; j < jstart + 32; ++j) {
            const float4 f = *(const float4*)&fsrc[j * DO + c4];
            const float2 pv = *(const float2*)&p[j][0];
            ax += pv.x * fmaxf(f.x + ftbAx, 0.f);
            ay += pv.x * fmaxf(f.y + ftbAy, 0.f);
            az += pv.x * fmaxf(f.z + ftbAz, 0.f);
            aw += pv.x * fmaxf(f.w + ftbAw, 0.f);
            bx += pv.y * fmaxf(f.x + ftbBx, 0.f);
            by += pv.y * fmaxf(f.y + ftbBy, 0.f);
            bz += pv.y * fmaxf(f.z + ftbBz, 0.f);
            bw_ += pv.y * fmaxf(f.w + ftbBw, 0.f);
        }

        *(float4*)&red[jg][0][c4] = make_float4(ax, ay, az, aw);
        *(float4*)&red[jg][1][c4] = make_float4(bx, by, bz, bw_);
        __syncthreads();

        if (tid < 256) {
            const int rr = tid >> 7;
            const int cc = tid & 127;
            float acc = 0.f;
#pragma unroll
            for (int g = 0; g < 16; ++g)
                acc += red[g][rr][cc];
            out[(i0 + rr) * DO + cc] = acc;
        }
    }
}

// ---------------------------------------------------------------------------
extern "C" void kernel_launch(void* const* d_in, const int* in_sizes, int n_in,
                              void* d_out, int out_size, void* d_ws, size_t ws_size,
                              hipStream_t stream) {
    const float* x   = (const float*)d_in[0];  // [512,128]
    const int*   adj = (const int*)  d_in[1];  // [512,512]
    const float* Wf  = (const float*)d_in[2];  // [128,256]
    const float* bf  = (const float*)d_in[3];  // [128]
    const float* Ww  = (const float*)d_in[4];  // [1,256]
    const float* bw  = (const float*)d_in[5];  // [1]
    float* out = (float*)d_out;

    float* WT   = (float*)d_ws;           // 128*256
    float* fsrc = WT + 128 * 256;         // 512*128
    float* ftgt = fsrc + N * DO;          // 512*128
    float* s    = ftgt + N * DO;          // 512
    float* t    = s + N;                  // 512

    void* args[] = {
        (void*)&x, (void*)&adj, (void*)&Wf, (void*)&bf, (void*)&Ww, (void*)&bw,
        (void*)&out, (void*)&WT, (void*)&fsrc, (void*)&ftgt, (void*)&s, (void*)&t
    };
    hipLaunchCooperativeKernel((void*)gat_fused_kernel,
                               dim3(256), dim3(512), args, 0, stream);
}

// Round 4
// 43.479 us; speedup vs baseline: 1.8423x; 1.8423x over previous
//
#include <hip/hip_runtime.h>
#include <math.h>

#define N   512
#define DI  128
#define DO  128
#define NBLK 256

// d_ws layout (floats): fsrc[512*128] | ftgt[512*128] | s[512] | t[512]
// barrier counter: at byte offset 1 MB (memset to 0 by kernel_launch each call)

struct SharedC {
    float p[N][2];           // 4 KB
    float red[16][2][DO];    // 16 KB
};
union SharedU {
    float wt[32][257];       // 32.9 KB  (proj phase: transposed Wf k-chunk)
    SharedC c;               // phase-2 arrays
};

__global__ __launch_bounds__(512, 1) void gat_onekernel(
    const float* __restrict__ x,
    const int*   __restrict__ adj,
    const float* __restrict__ Wf,
    const float* __restrict__ bf,
    const float* __restrict__ Ww,
    const float* __restrict__ bw,
    float* __restrict__ out,      // [0..N*DO) = o, [N*DO..) = a_att
    float* __restrict__ fsrc,
    float* __restrict__ ftgt,
    float* __restrict__ s,
    float* __restrict__ t,
    unsigned* __restrict__ cnt)
{
    const int b   = blockIdx.x;
    const int tid = threadIdx.x;   // 0..511
    const int j0  = b * 2;         // this block's two rows

    __shared__ SharedU sh;
    __shared__ float rmax[2][4], rsum[2][4];

    // ================= phase P: projections (rows j0, j0+1) =================
    {
        const int r = tid >> 8;        // row 0/1
        const int c = tid & 255;       // output column 0..255
        const float* __restrict__ xr = x + (j0 + r) * DI;

        float acc = 0.f;
        for (int kc = 0; kc < DI; kc += 32) {
            // stage transposed Wf chunk: wt[k][c] = Wf[c&127][(c>>7)*128 + kc + k]
            for (int q = 0; q < 4; ++q) {
                const int L    = q * 512 + tid;     // 0..2047
                const int f4   = L & 7;
                const int row  = (L >> 3) & 127;
                const int half = L >> 10;           // 0/1
                const float4 w = *(const float4*)&Wf[row * 256 + half * 128 + kc + f4 * 4];
                const int cc = half * 128 + row;
                sh.wt[f4 * 4 + 0][cc] = w.x;
                sh.wt[f4 * 4 + 1][cc] = w.y;
                sh.wt[f4 * 4 + 2][cc] = w.z;
                sh.wt[f4 * 4 + 3][cc] = w.w;
            }
            __syncthreads();
#pragma unroll
            for (int kk = 0; kk < 32; ++kk)
                acc += xr[kc + kk] * sh.wt[kk][c];
            __syncthreads();
        }
        if (c < DO) fsrc[(j0 + r) * DO + c] = acc;
        else        ftgt[(j0 + r) * DO + (c - DO)] = acc;

        // attention scalars s[j], t[j]: waves 0..3 -> (row, s|t)
        const int w = tid >> 6;
        if (w < 4) {
            const int row  = j0 + (w >> 1);
            const int half = (w & 1) * DI;
            const int l    = tid & 63;
            float v = x[row * DI + l] * Ww[half + l]
                    + x[row * DI + 64 + l] * Ww[half + 64 + l];
            for (int off = 32; off >= 1; off >>= 1)
                v += __shfl_down(v, off);
            if (l == 0) {
                if ((w & 1) == 0) s[row] = v;
                else              t[row] = v;
            }
        }
    }

    // ================= grid barrier (release/acquire, 1 block/CU) ============
    __syncthreads();   // drains each wave's global stores (vmcnt(0)) before arrival
    if (tid == 0) {
        __hip_atomic_fetch_add(cnt, 1u, __ATOMIC_RELEASE, __HIP_MEMORY_SCOPE_AGENT);
        while (__hip_atomic_load(cnt, __ATOMIC_RELAXED, __HIP_MEMORY_SCOPE_AGENT) < NBLK)
            __builtin_amdgcn_s_sleep(2);
    }
    __syncthreads();
    __builtin_amdgcn_fence(__ATOMIC_ACQUIRE, "agent");  // invalidate stale L1/L2

    // ================= phase 2: softmax + weighted ReLU contraction ==========
    {
        const int i0 = j0;
        const int r  = tid >> 8;       // row 0/1
        const int jj = tid & 255;      // handles j = jj, jj+256
        const int i  = i0 + r;
        const float t_i = t[i] + bw[0];

        const float sc0 = s[jj] + t_i;
        const float sc1 = s[jj + 256] + t_i;
        const float v0 = (adj[i * N + jj] > 0)       ? sc0 : -1e16f;
        const float v1 = (adj[i * N + jj + 256] > 0) ? sc1 : -1e16f;

        const int wr = (tid >> 6) & 3;
        float m = fmaxf(v0, v1);
        for (int off = 32; off >= 1; off >>= 1)
            m = fmaxf(m, __shfl_down(m, off));
        if ((tid & 63) == 0) rmax[r][wr] = m;
        __syncthreads();
        m = fmaxf(fmaxf(rmax[r][0], rmax[r][1]), fmaxf(rmax[r][2], rmax[r][3]));

        const float e0 = __expf(v0 - m);
        const float e1 = __expf(v1 - m);
        float sum = e0 + e1;
        for (int off = 32; off >= 1; off >>= 1)
            sum += __shfl_down(sum, off);
        if ((tid & 63) == 0) rsum[r][wr] = sum;
        __syncthreads();
        sum = rsum[r][0] + rsum[r][1] + rsum[r][2] + rsum[r][3];
        const float inv = 1.0f / sum;

        const float p0 = e0 * inv;
        const float p1 = e1 * inv;
        sh.c.p[jj][r]       = p0;
        sh.c.p[jj + 256][r] = p1;
        out[N * DO + i * N + jj]       = p0;
        out[N * DO + i * N + jj + 256] = p1;
        __syncthreads();

        // weighted ReLU contraction: 16 j-groups x 32 d-float4-groups
        const int c4 = (tid & 31) * 4;
        const int jg = tid >> 5;

        const float4 fA = *(const float4*)&ftgt[i0 * DO + c4];
        const float4 fB = *(const float4*)&ftgt[(i0 + 1) * DO + c4];
        const float4 bb = *(const float4*)&bf[c4];
        const float ftbAx = fA.x + bb.x, ftbAy = fA.y + bb.y,
                    ftbAz = fA.z + bb.z, ftbAw = fA.w + bb.w;
        const float ftbBx = fB.x + bb.x, ftbBy = fB.y + bb.y,
                    ftbBz = fB.z + bb.z, ftbBw = fB.w + bb.w;

        float ax = 0.f, ay = 0.f, az = 0.f, aw = 0.f;
        float bx = 0.f, by = 0.f, bz = 0.f, bw_ = 0.f;

        const int jstart = jg * 32;
#pragma unroll 8
        for (int j = jstart; j < jstart + 32; ++j) {
            const float4 f = *(const float4*)&fsrc[j * DO + c4];
            const float2 pv = *(const float2*)&sh.c.p[j][0];
            ax  += pv.x * fmaxf(f.x + ftbAx, 0.f);
            ay  += pv.x * fmaxf(f.y + ftbAy, 0.f);
            az  += pv.x * fmaxf(f.z + ftbAz, 0.f);
            aw  += pv.x * fmaxf(f.w + ftbAw, 0.f);
            bx  += pv.y * fmaxf(f.x + ftbBx, 0.f);
            by  += pv.y * fmaxf(f.y + ftbBy, 0.f);
            bz  += pv.y * fmaxf(f.z + ftbBz, 0.f);
            bw_ += pv.y * fmaxf(f.w + ftbBw, 0.f);
        }

        *(float4*)&sh.c.red[jg][0][c4] = make_float4(ax, ay, az, aw);
        *(float4*)&sh.c.red[jg][1][c4] = make_float4(bx, by, bz, bw_);
        __syncthreads();

        if (tid < 256) {
            const int rr = tid >> 7;
            const int cc = tid & 127;
            float acc = 0.f;
#pragma unroll
            for (int g = 0; g < 16; ++g)
                acc += sh.c.red[g][rr][cc];
            out[(i0 + rr) * DO + cc] = acc;
        }
    }
}

// ---------------------------------------------------------------------------
extern "C" void kernel_launch(void* const* d_in, const int* in_sizes, int n_in,
                              void* d_out, int out_size, void* d_ws, size_t ws_size,
                              hipStream_t stream) {
    const float* x   = (const float*)d_in[0];  // [512,128]
    const int*   adj = (const int*)  d_in[1];  // [512,512]
    const float* Wf  = (const float*)d_in[2];  // [128,256]
    const float* bf  = (const float*)d_in[3];  // [128]
    const float* Ww  = (const float*)d_in[4];  // [1,256]
    const float* bw  = (const float*)d_in[5];  // [1]
    float* out = (float*)d_out;

    float* fsrc = (float*)d_ws;           // 512*128
    float* ftgt = fsrc + N * DO;          // 512*128
    float* s    = ftgt + N * DO;          // 512
    float* t    = s + N;                  // 512
    unsigned* cnt = (unsigned*)((char*)d_ws + (1u << 20));  // barrier counter

    hipMemsetAsync(cnt, 0, sizeof(unsigned), stream);
    gat_onekernel<<<dim3(NBLK), dim3(512), 0, stream>>>(
        x, adj, Wf, bf, Ww, bw, out, fsrc, ftgt, s, t, cnt);
}

// Round 5
// 36.299 us; speedup vs baseline: 2.2067x; 1.1978x over previous
//
#include <hip/hip_runtime.h>
#include <math.h>

#define N   512
#define DI  128
#define DO  128
#define NBLK 256

// d_ws layout (floats): fsrc[512*128] | ftgt[512*128] | s[512] | t[512]
// barrier slots: 256 uints at byte offset 1 MB. NO reset needed: each block
// increments its own slot once per call; slots stay mutually equal between
// calls (any uniform start value works, incl. 0xAAAAAAAA poison).

struct SharedC {
    float p[N][2];           // 4 KB
    float red[16][2][DO];    // 16 KB
};
union SharedU {
    float wt[32][257];       // 32.9 KB  (proj phase: transposed Wf k-chunk)
    SharedC c;               // phase-2 arrays
};

__global__ __launch_bounds__(512, 1) void gat_onekernel(
    const float* __restrict__ x,
    const int*   __restrict__ adj,
    const float* __restrict__ Wf,
    const float* __restrict__ bf,
    const float* __restrict__ Ww,
    const float* __restrict__ bw,
    float* __restrict__ out,      // [0..N*DO) = o, [N*DO..) = a_att
    float* __restrict__ fsrc,
    float* __restrict__ ftgt,
    float* __restrict__ s,
    float* __restrict__ t,
    unsigned* __restrict__ slots)
{
    const int b   = blockIdx.x;
    const int tid = threadIdx.x;   // 0..511
    const int j0  = b * 2;         // this block's two rows

    __shared__ SharedU sh;
    __shared__ float rmax[2][4], rsum[2][4];
    __shared__ unsigned bar_target;

    // ================= phase P: projections (rows j0, j0+1) =================
    {
        const int r = tid >> 8;        // row 0/1
        const int c = tid & 255;       // output column 0..255
        const float* __restrict__ xr = x + (j0 + r) * DI;

        float acc = 0.f;
        for (int kc = 0; kc < DI; kc += 32) {
            // stage transposed Wf chunk: wt[k][c] = Wf[c&127][(c>>7)*128 + kc + k]
            for (int q = 0; q < 4; ++q) {
                const int L    = q * 512 + tid;     // 0..2047
                const int f4   = L & 7;
                const int row  = (L >> 3) & 127;
                const int half = L >> 10;           // 0/1
                const float4 w = *(const float4*)&Wf[row * 256 + half * 128 + kc + f4 * 4];
                const int cc = half * 128 + row;
                sh.wt[f4 * 4 + 0][cc] = w.x;
                sh.wt[f4 * 4 + 1][cc] = w.y;
                sh.wt[f4 * 4 + 2][cc] = w.z;
                sh.wt[f4 * 4 + 3][cc] = w.w;
            }
            __syncthreads();
#pragma unroll
            for (int kk = 0; kk < 32; ++kk)
                acc += xr[kc + kk] * sh.wt[kk][c];
            __syncthreads();
        }
        if (c < DO) fsrc[(j0 + r) * DO + c] = acc;
        else        ftgt[(j0 + r) * DO + (c - DO)] = acc;

        // attention scalars s[j], t[j]: waves 0..3 -> (row, s|t)
        const int w = tid >> 6;
        if (w < 4) {
            const int row  = j0 + (w >> 1);
            const int half = (w & 1) * DI;
            const int l    = tid & 63;
            float v = x[row * DI + l] * Ww[half + l]
                    + x[row * DI + 64 + l] * Ww[half + 64 + l];
            for (int off = 32; off >= 1; off >>= 1)
                v += __shfl_down(v, off);
            if (l == 0) {
                if ((w & 1) == 0) s[row] = v;
                else              t[row] = v;
            }
        }
    }

    // ================= grid barrier (self-resetting slot array) =============
    __syncthreads();   // all waves' global stores drained (vmcnt 0) before arrival
    if (tid == 0) {
        const unsigned my =
            __hip_atomic_load(&slots[b], __ATOMIC_RELAXED, __HIP_MEMORY_SCOPE_AGENT) + 1u;
        __hip_atomic_store(&slots[b], my, __ATOMIC_RELEASE, __HIP_MEMORY_SCOPE_AGENT);
        bar_target = my;
    }
    __syncthreads();
    {
        const unsigned tg = bar_target;
        if (tid < NBLK) {
            // bounded spin: correct path exits in ~a microsecond; bound only
            // guards against pathological init (fail fast instead of hang)
            for (long it = 0; it < (1L << 27); ++it) {
                if (__hip_atomic_load(&slots[tid], __ATOMIC_RELAXED,
                                      __HIP_MEMORY_SCOPE_AGENT) >= tg) break;
                __builtin_amdgcn_s_sleep(1);
            }
        }
        __syncthreads();
        __builtin_amdgcn_fence(__ATOMIC_ACQUIRE, "agent");
    }

    // ================= phase 2: softmax + weighted ReLU contraction ==========
    {
        const int i0 = j0;
        const int r  = tid >> 8;       // row 0/1
        const int jj = tid & 255;      // handles j = jj, jj+256
        const int i  = i0 + r;
        const float t_i = t[i] + bw[0];

        const float sc0 = s[jj] + t_i;
        const float sc1 = s[jj + 256] + t_i;
        const float v0 = (adj[i * N + jj] > 0)       ? sc0 : -1e16f;
        const float v1 = (adj[i * N + jj + 256] > 0) ? sc1 : -1e16f;

        const int wr = (tid >> 6) & 3;
        float m = fmaxf(v0, v1);
        for (int off = 32; off >= 1; off >>= 1)
            m = fmaxf(m, __shfl_down(m, off));
        if ((tid & 63) == 0) rmax[r][wr] = m;
        __syncthreads();
        m = fmaxf(fmaxf(rmax[r][0], rmax[r][1]), fmaxf(rmax[r][2], rmax[r][3]));

        const float e0 = __expf(v0 - m);
        const float e1 = __expf(v1 - m);
        float sum = e0 + e1;
        for (int off = 32; off >= 1; off >>= 1)
            sum += __shfl_down(sum, off);
        if ((tid & 63) == 0) rsum[r][wr] = sum;
        __syncthreads();
        sum = rsum[r][0] + rsum[r][1] + rsum[r][2] + rsum[r][3];
        const float inv = 1.0f / sum;

        const float p0 = e0 * inv;
        const float p1 = e1 * inv;
        sh.c.p[jj][r]       = p0;
        sh.c.p[jj + 256][r] = p1;
        out[N * DO + i * N + jj]       = p0;
        out[N * DO + i * N + jj + 256] = p1;
        __syncthreads();

        // weighted ReLU contraction: 16 j-groups x 32 d-float4-groups
        const int c4 = (tid & 31) * 4;
        const int jg = tid >> 5;

        const float4 fA = *(const float4*)&ftgt[i0 * DO + c4];
        const float4 fB = *(const float4*)&ftgt[(i0 + 1) * DO + c4];
        const float4 bb = *(const float4*)&bf[c4];
        const float ftbAx = fA.x + bb.x, ftbAy = fA.y + bb.y,
                    ftbAz = fA.z + bb.z, ftbAw = fA.w + bb.w;
        const float ftbBx = fB.x + bb.x, ftbBy = fB.y + bb.y,
                    ftbBz = fB.z + bb.z, ftbBw = fB.w + bb.w;

        float ax = 0.f, ay = 0.f, az = 0.f, aw = 0.f;
        float bx = 0.f, by = 0.f, bz = 0.f, bw_ = 0.f;

        const int jstart = jg * 32;
#pragma unroll 8
        for (int j = jstart; j < jstart + 32; ++j) {
            const float4 f = *(const float4*)&fsrc[j * DO + c4];
            const float2 pv = *(const float2*)&sh.c.p[j][0];
            ax  += pv.x * fmaxf(f.x + ftbAx, 0.f);
            ay  += pv.x * fmaxf(f.y + ftbAy, 0.f);
            az  += pv.x * fmaxf(f.z + ftbAz, 0.f);
            aw  += pv.x * fmaxf(f.w + ftbAw, 0.f);
            bx  += pv.y * fmaxf(f.x + ftbBx, 0.f);
            by  += pv.y * fmaxf(f.y + ftbBy, 0.f);
            bz  += pv.y * fmaxf(f.z + ftbBz, 0.f);
            bw_ += pv.y * fmaxf(f.w + ftbBw, 0.f);
        }

        *(float4*)&sh.c.red[jg][0][c4] = make_float4(ax, ay, az, aw);
        *(float4*)&sh.c.red[jg][1][c4] = make_float4(bx, by, bz, bw_);
        __syncthreads();

        if (tid < 256) {
            const int rr = tid >> 7;
            const int cc = tid & 127;
            float acc = 0.f;
#pragma unroll
            for (int g = 0; g < 16; ++g)
                acc += sh.c.red[g][rr][cc];
            out[(i0 + rr) * DO + cc] = acc;
        }
    }
}

// ---------------------------------------------------------------------------
extern "C" void kernel_launch(void* const* d_in, const int* in_sizes, int n_in,
                              void* d_out, int out_size, void* d_ws, size_t ws_size,
                              hipStream_t stream) {
    const float* x   = (const float*)d_in[0];  // [512,128]
    const int*   adj = (const int*)  d_in[1];  // [512,512]
    const float* Wf  = (const float*)d_in[2];  // [128,256]
    const float* bf  = (const float*)d_in[3];  // [128]
    const float* Ww  = (const float*)d_in[4];  // [1,256]
    const float* bw  = (const float*)d_in[5];  // [1]
    float* out = (float*)d_out;

    float* fsrc = (float*)d_ws;           // 512*128
    float* ftgt = fsrc + N * DO;          // 512*128
    float* s    = ftgt + N * DO;          // 512
    float* t    = s + N;                  // 512
    unsigned* slots = (unsigned*)((char*)d_ws + (1u << 20));  // 256 uints

    gat_onekernel<<<dim3(NBLK), dim3(512), 0, stream>>>(
        x, adj, Wf, bf, Ww, bw, out, fsrc, ftgt, s, t, slots);
}

// Round 6
// 20.467 us; speedup vs baseline: 3.9138x; 1.7736x over previous
//
#include <hip/hip_runtime.h>
#include <math.h>

#define N   512
#define DI  128
#define DO  128

// d_ws layout (floats): fsrc[512*128] | ftgt[512*128] | s[512] | t[512]

// ---------------------------------------------------------------------------
// K1: projections. 256 blocks x 512 threads, 2 rows per block.
// Stages transposed Wf chunks in LDS (wt[32][257], conflict-free), so Wf
// global reads are float4-coalesced. Also computes s[j], t[j].
// ---------------------------------------------------------------------------
__global__ __launch_bounds__(512, 1) void proj_kernel(
    const float* __restrict__ x,
    const float* __restrict__ Wf,
    const float* __restrict__ Ww,
    float* __restrict__ fsrc,
    float* __restrict__ ftgt,
    float* __restrict__ s,
    float* __restrict__ t)
{
    const int b   = blockIdx.x;
    const int tid = threadIdx.x;   // 0..511
    const int j0  = b * 2;

    __shared__ float wt[32][257];  // 32.9 KB

    const int r = tid >> 8;        // row 0/1
    const int c = tid & 255;       // output column 0..255
    const float* __restrict__ xr = x + (j0 + r) * DI;

    float acc = 0.f;
    for (int kc = 0; kc < DI; kc += 32) {
        // stage transposed Wf chunk: wt[k][c] = Wf[c&127][(c>>7)*128 + kc + k]
        for (int q = 0; q < 4; ++q) {
            const int L    = q * 512 + tid;     // 0..2047
            const int f4   = L & 7;
            const int row  = (L >> 3) & 127;
            const int half = L >> 10;           // 0/1
            const float4 w = *(const float4*)&Wf[row * 256 + half * 128 + kc + f4 * 4];
            const int cc = half * 128 + row;
            wt[f4 * 4 + 0][cc] = w.x;
            wt[f4 * 4 + 1][cc] = w.y;
            wt[f4 * 4 + 2][cc] = w.z;
            wt[f4 * 4 + 3][cc] = w.w;
        }
        __syncthreads();
#pragma unroll
        for (int kk = 0; kk < 32; ++kk)
            acc += xr[kc + kk] * wt[kk][c];
        __syncthreads();
    }
    if (c < DO) fsrc[(j0 + r) * DO + c] = acc;
    else        ftgt[(j0 + r) * DO + (c - DO)] = acc;

    // attention scalars s[j], t[j]: waves 0..3 -> (row, s|t)
    const int w = tid >> 6;
    if (w < 4) {
        const int row  = j0 + (w >> 1);
        const int half = (w & 1) * DI;
        const int l    = tid & 63;
        float v = x[row * DI + l] * Ww[half + l]
                + x[row * DI + 64 + l] * Ww[half + 64 + l];
        for (int off = 32; off >= 1; off >>= 1)
            v += __shfl_down(v, off);
        if (l == 0) {
            if ((w & 1) == 0) s[row] = v;
            else              t[row] = v;
        }
    }
}

// ---------------------------------------------------------------------------
// K2: softmax + weighted ReLU contraction. 256 blocks x 512 threads,
// 2 output rows per block.
// ---------------------------------------------------------------------------
__global__ __launch_bounds__(512, 1) void gat_kernel(
    const int*   __restrict__ adj,
    const float* __restrict__ fsrc,
    const float* __restrict__ ftgt,
    const float* __restrict__ s,
    const float* __restrict__ t,
    const float* __restrict__ bf,
    const float* __restrict__ bw,
    float* __restrict__ out)   // [0..N*DO) = o, [N*DO..) = a_att
{
    const int i0  = blockIdx.x * 2;
    const int tid = threadIdx.x;   // 0..511

    __shared__ float p[N][2];          // 4 KB
    __shared__ float red[16][2][DO];   // 16 KB
    __shared__ float rmax[2][4], rsum[2][4];

    const int r  = tid >> 8;       // row 0/1
    const int jj = tid & 255;      // handles j = jj, jj+256
    const int i  = i0 + r;
    const float t_i = t[i] + bw[0];

    const float sc0 = s[jj] + t_i;
    const float sc1 = s[jj + 256] + t_i;
    const float v0 = (adj[i * N + jj] > 0)       ? sc0 : -1e16f;
    const float v1 = (adj[i * N + jj + 256] > 0) ? sc1 : -1e16f;

    const int wr = (tid >> 6) & 3;
    float m = fmaxf(v0, v1);
    for (int off = 32; off >= 1; off >>= 1)
        m = fmaxf(m, __shfl_down(m, off));
    if ((tid & 63) == 0) rmax[r][wr] = m;
    __syncthreads();
    m = fmaxf(fmaxf(rmax[r][0], rmax[r][1]), fmaxf(rmax[r][2], rmax[r][3]));

    const float e0 = __expf(v0 - m);
    const float e1 = __expf(v1 - m);
    float sum = e0 + e1;
    for (int off = 32; off >= 1; off >>= 1)
        sum += __shfl_down(sum, off);
    if ((tid & 63) == 0) rsum[r][wr] = sum;
    __syncthreads();
    sum = rsum[r][0] + rsum[r][1] + rsum[r][2] + rsum[r][3];
    const float inv = 1.0f / sum;

    const float p0 = e0 * inv;
    const float p1 = e1 * inv;
    p[jj][r]       = p0;
    p[jj + 256][r] = p1;
    out[N * DO + i * N + jj]       = p0;
    out[N * DO + i * N + jj + 256] = p1;
    __syncthreads();

    // weighted ReLU contraction: 16 j-groups x 32 d-float4-groups
    const int c4 = (tid & 31) * 4;
    const int jg = tid >> 5;

    const float4 fA = *(const float4*)&ftgt[i0 * DO + c4];
    const float4 fB = *(const float4*)&ftgt[(i0 + 1) * DO + c4];
    const float4 bb = *(const float4*)&bf[c4];
    const float ftbAx = fA.x + bb.x, ftbAy = fA.y + bb.y,
                ftbAz = fA.z + bb.z, ftbAw = fA.w + bb.w;
    const float ftbBx = fB.x + bb.x, ftbBy = fB.y + bb.y,
                ftbBz = fB.z + bb.z, ftbBw = fB.w + bb.w;

    float ax = 0.f, ay = 0.f, az = 0.f, aw = 0.f;
    float bx = 0.f, by = 0.f, bz = 0.f, bw_ = 0.f;

    const int jstart = jg * 32;
#pragma unroll 8
    for (int j = jstart; j < jstart + 32; ++j) {
        const float4 f = *(const float4*)&fsrc[j * DO + c4];
        const float2 pv = *(const float2*)&p[j][0];
        ax  += pv.x * fmaxf(f.x + ftbAx, 0.f);
        ay  += pv.x * fmaxf(f.y + ftbAy, 0.f);
        az  += pv.x * fmaxf(f.z + ftbAz, 0.f);
        aw  += pv.x * fmaxf(f.w + ftbAw, 0.f);
        bx  += pv.y * fmaxf(f.x + ftbBx, 0.f);
        by  += pv.y * fmaxf(f.y + ftbBy, 0.f);
        bz  += pv.y * fmaxf(f.z + ftbBz, 0.f);
        bw_ += pv.y * fmaxf(f.w + ftbBw, 0.f);
    }

    *(float4*)&red[jg][0][c4] = make_float4(ax, ay, az, aw);
    *(float4*)&red[jg][1][c4] = make_float4(bx, by, bz, bw_);
    __syncthreads();

    if (tid < 256) {
        const int rr = tid >> 7;
        const int cc = tid & 127;
        float acc = 0.f;
#pragma unroll
        for (int g = 0; g < 16; ++g)
            acc += red[g][rr][cc];
        out[(i0 + rr) * DO + cc] = acc;
    }
}

// ---------------------------------------------------------------------------
extern "C" void kernel_launch(void* const* d_in, const int* in_sizes, int n_in,
                              void* d_out, int out_size, void* d_ws, size_t ws_size,
                              hipStream_t stream) {
    const float* x   = (const float*)d_in[0];  // [512,128]
    const int*   adj = (const int*)  d_in[1];  // [512,512]
    const float* Wf  = (const float*)d_in[2];  // [128,256]
    const float* bf  = (const float*)d_in[3];  // [128]
    const float* Ww  = (const float*)d_in[4];  // [1,256]
    const float* bw  = (const float*)d_in[5];  // [1]
    float* out = (float*)d_out;

    float* fsrc = (float*)d_ws;           // 512*128
    float* ftgt = fsrc + N * DO;          // 512*128
    float* s    = ftgt + N * DO;          // 512
    float* t    = s + N;                  // 512

    proj_kernel<<<dim3(256), dim3(512), 0, stream>>>(x, Wf, Ww, fsrc, ftgt, s, t);
    gat_kernel <<<dim3(256), dim3(512), 0, stream>>>(adj, fsrc, ftgt, s, t, bf, bw, out);
}